// Round 5
// baseline (42.565 us; speedup 1.0000x reference)
//
#include <hip/hip_runtime.h>

#define NSTEP 32
// DIM = 62 monomials of degree 1..5 over (x0,x1), collapsed per (step,stage)
// into 30 gradient coefficients:
//   g[0..14]  dP/dx0, triangular rows by e0 (widths 5,4,3,2,1; inner Horner in x1)
//   g[15..29] dP/dx1, rows by e1 (inner Horner in x0)
// Global table layout (padded for s_load_dwordx16 merging):
//   G[(step*4 + stage)*32 + k], 128 stages x 32 floats = 16 KB.
// Main kernel streams each stage into SGPRs (uniform scalar loads) with a
// stage-granular double buffer; FMAs consume coefficients as SGPR operands.

// ---------------------------------------------------------------------------
__global__ void prep_kernel(const float* __restrict__ Aw, const float* __restrict__ Bw,
                            const float* __restrict__ Cw, const float* __restrict__ Dw,
                            float* __restrict__ G) {
    int t = blockIdx.x * blockDim.x + threadIdx.x;
    if (t >= NSTEP * 4) return;
    int stepi = t >> 2, which = t & 3;
    const float* w;
    switch (which) { case 0: w = Aw; break; case 1: w = Bw; break;
                     case 2: w = Cw; break; default: w = Dw; }
    w += stepi * 62;

    float c[6][6];
#pragma unroll
    for (int a = 0; a < 6; ++a)
#pragma unroll
        for (int b = 0; b < 6; ++b) c[a][b] = 0.f;
    // degree-d flat index f: bits of f are the monomial indices; popcount = power of x1
#pragma unroll
    for (int d = 1; d <= 5; ++d)
#pragma unroll
        for (int f = 0; f < (1 << d); ++f) {
            int b = __popc(f);
            c[d - b][b] += w[(1 << d) - 2 + f];
        }

    float* dst = G + t * 32;
    int k = 0;
#pragma unroll
    for (int e0 = 0; e0 <= 4; ++e0)
#pragma unroll
        for (int e1 = 0; e1 + e0 <= 4; ++e1)
            dst[k++] = (float)(e0 + 1) * c[e0 + 1][e1];
#pragma unroll
    for (int e1 = 0; e1 <= 4; ++e1)
#pragma unroll
        for (int e0 = 0; e0 + e1 <= 4; ++e0)
            dst[k++] = (float)(e1 + 1) * c[e0][e1 + 1];
    dst[30] = 0.f; dst[31] = 0.f;
}

// ---------------------------------------------------------------------------
__device__ __forceinline__ const float* uniform_ptr(const float* p) {
    uint64_t v = (uint64_t)p;
    uint32_t lo = __builtin_amdgcn_readfirstlane((uint32_t)v);
    uint32_t hi = __builtin_amdgcn_readfirstlane((uint32_t)(v >> 32));
    return (const float*)(((uint64_t)hi << 32) | lo);
}

__device__ __forceinline__ void loadc(const float* __restrict__ gS, float (&g)[30]) {
#pragma unroll
    for (int k = 0; k < 30; ++k) g[k] = gS[k];   // uniform addr -> s_load
}

__device__ __forceinline__ void pgrad(const float (&g)[30], float x0, float x1,
                                      float& d0, float& d1) {
    float r0 = fmaf(fmaf(fmaf(fmaf(g[4], x1, g[3]), x1, g[2]), x1, g[1]), x1, g[0]);
    float r1 = fmaf(fmaf(fmaf(g[8], x1, g[7]), x1, g[6]), x1, g[5]);
    float r2 = fmaf(fmaf(g[11], x1, g[10]), x1, g[9]);
    float r3 = fmaf(g[13], x1, g[12]);
    float r4 = g[14];
    d0 = fmaf(fmaf(fmaf(fmaf(r4, x0, r3), x0, r2), x0, r1), x0, r0);

    float s0 = fmaf(fmaf(fmaf(fmaf(g[19], x0, g[18]), x0, g[17]), x0, g[16]), x0, g[15]);
    float s1 = fmaf(fmaf(fmaf(g[23], x0, g[22]), x0, g[21]), x0, g[20]);
    float s2 = fmaf(fmaf(g[26], x0, g[25]), x0, g[24]);
    float s3 = fmaf(g[28], x0, g[27]);
    float s4 = g[29];
    d1 = fmaf(fmaf(fmaf(fmaf(s4, x1, s3), x1, s2), x1, s1), x1, s0);
}

__global__ void __launch_bounds__(256, 1)
sympl_main(const float* __restrict__ zin, const float* __restrict__ Gp,
           const int* __restrict__ nsp, float* __restrict__ zout, int batch) {
    const float* G = uniform_ptr(Gp);

    int lt = threadIdx.x;
    int idx = blockIdx.x * 256 + lt;
    bool active = idx < batch;

    float4 zv = make_float4(0.f, 0.f, 0.f, 0.f);
    if (active) zv = reinterpret_cast<const float4*>(zin)[idx];
    float dt  = 1.0f / (32.0f * (float)nsp[0]);
    float hdt = 0.5f * dt;

    float q0 = zv.x, q1 = zv.y, p0 = zv.z, p1 = zv.w;

    float gX[30], gY[30];
    loadc(G, gX);                                  // stage 0 (step 0, A)

#pragma unroll 1
    for (int s = 0; s < NSTEP; ++s) {
        const float* base = G + s * 128;

        // ---- stage A (from X); prefetch B into Y ----
        loadc(base + 32, gY);
        float dA0, dA1; pgrad(gX, p0, p1, dA0, dA1);
        q0 = fmaf(dA0, hdt, q0); q1 = fmaf(dA1, hdt, q1);

        // ---- stage B (from Y); prefetch C into X ----
        loadc(base + 64, gX);
        float dB0, dB1; pgrad(gY, q0, q1, dB0, dB1);
        p0 = fmaf(-dB0, dt, p0); p1 = fmaf(-dB1, dt, p1);
        q0 = fmaf(dA0, hdt, q0); q1 = fmaf(dA1, hdt, q1);

        float u0 = q1, u1 = p0, v0 = q0, v1 = p1;

        // ---- stage C (from X); prefetch D into Y ----
        loadc(base + 96, gY);
        float dC0, dC1; pgrad(gX, v0, v1, dC0, dC1);
        u0 = fmaf(dC1, hdt, u0); u1 = fmaf(-dC0, hdt, u1);

        // ---- stage D (from Y); prefetch next step's A into X ----
        const float* nbase = (s + 1 < NSTEP) ? base + 128 : base;
        loadc(nbase, gX);
        float dD0, dD1; pgrad(gY, u0, u1, dD0, dD1);
        v0 = fmaf(dD1, dt, v0); v1 = fmaf(-dD0, dt, v1);
        u0 = fmaf(dC1, hdt, u0); u1 = fmaf(-dC0, hdt, u1);

        q0 = v0; q1 = u0; p0 = u1; p1 = v1;        // z = [v0, u0, u1, v1]
    }

    if (active) {
        float4 o; o.x = q0; o.y = q1; o.z = p0; o.w = p1;
        reinterpret_cast<float4*>(zout)[idx] = o;
    }
}

extern "C" void kernel_launch(void* const* d_in, const int* in_sizes, int n_in,
                              void* d_out, int out_size, void* d_ws, size_t ws_size,
                              hipStream_t stream) {
    const float* z  = (const float*)d_in[0];
    const float* Aw = (const float*)d_in[1];
    const float* Bw = (const float*)d_in[2];
    const float* Cw = (const float*)d_in[3];
    const float* Dw = (const float*)d_in[4];
    const int*   ns = (const int*)d_in[5];
    float* G = (float*)d_ws;   // 128 * 32 floats = 16 KB

    prep_kernel<<<1, 128, 0, stream>>>(Aw, Bw, Cw, Dw, G);

    int batch = in_sizes[0] / 4;
    int threads = 256;
    int blocks = (batch + threads - 1) / threads;
    sympl_main<<<blocks, threads, 0, stream>>>(z, G, ns, (float*)d_out, batch);
}

// Round 6
// 42.563 us; speedup vs baseline: 1.0001x; 1.0001x over previous
//
#include <hip/hip_runtime.h>
#include <stdint.h>

#define NSTEP 32
// DIM = 62 monomials of degree 1..5 over (x0,x1), collapsed per (step,stage)
// into 30 gradient coefficients:
//   g[0..14]  dP/dx0, triangular rows by e0 (widths 5,4,3,2,1; inner Horner in x1)
//   g[15..29] dP/dx1, rows by e1 (inner Horner in x0)
// Global table: G[(step*4 + stage)*32 + k], 128 stages x 32 floats = 16 KB.
// Main kernel reads the table through the CONSTANT address space (4) at
// wave-uniform addresses -> true s_load into SGPRs (scalar pipe + K$),
// zero per-lane replication; FMAs consume coefficients as SGPR operands.

// ---------------------------------------------------------------------------
__global__ void prep_kernel(const float* __restrict__ Aw, const float* __restrict__ Bw,
                            const float* __restrict__ Cw, const float* __restrict__ Dw,
                            float* __restrict__ G) {
    int t = blockIdx.x * blockDim.x + threadIdx.x;
    if (t >= NSTEP * 4) return;
    int stepi = t >> 2, which = t & 3;
    const float* w;
    switch (which) { case 0: w = Aw; break; case 1: w = Bw; break;
                     case 2: w = Cw; break; default: w = Dw; }
    w += stepi * 62;

    float c[6][6];
#pragma unroll
    for (int a = 0; a < 6; ++a)
#pragma unroll
        for (int b = 0; b < 6; ++b) c[a][b] = 0.f;
    // degree-d flat index f: bits of f are the monomial indices; popcount = power of x1
#pragma unroll
    for (int d = 1; d <= 5; ++d)
#pragma unroll
        for (int f = 0; f < (1 << d); ++f) {
            int b = __popc(f);
            c[d - b][b] += w[(1 << d) - 2 + f];
        }

    float* dst = G + t * 32;
    int k = 0;
#pragma unroll
    for (int e0 = 0; e0 <= 4; ++e0)
#pragma unroll
        for (int e1 = 0; e1 + e0 <= 4; ++e1)
            dst[k++] = (float)(e0 + 1) * c[e0 + 1][e1];
#pragma unroll
    for (int e1 = 0; e1 <= 4; ++e1)
#pragma unroll
        for (int e0 = 0; e0 + e1 <= 4; ++e0)
            dst[k++] = (float)(e1 + 1) * c[e0][e1 + 1];
    dst[30] = 0.f; dst[31] = 0.f;
}

// ---------------------------------------------------------------------------
typedef __attribute__((address_space(4))) const float cfloat_t;

__device__ __forceinline__ void loadc(cfloat_t* __restrict__ gS, float (&g)[30]) {
#pragma unroll
    for (int k = 0; k < 30; ++k) g[k] = gS[k];   // uniform + constant AS -> s_load
}

__device__ __forceinline__ void pgrad(const float (&g)[30], float x0, float x1,
                                      float& d0, float& d1) {
    float r0 = fmaf(fmaf(fmaf(fmaf(g[4], x1, g[3]), x1, g[2]), x1, g[1]), x1, g[0]);
    float r1 = fmaf(fmaf(fmaf(g[8], x1, g[7]), x1, g[6]), x1, g[5]);
    float r2 = fmaf(fmaf(g[11], x1, g[10]), x1, g[9]);
    float r3 = fmaf(g[13], x1, g[12]);
    float r4 = g[14];
    d0 = fmaf(fmaf(fmaf(fmaf(r4, x0, r3), x0, r2), x0, r1), x0, r0);

    float s0 = fmaf(fmaf(fmaf(fmaf(g[19], x0, g[18]), x0, g[17]), x0, g[16]), x0, g[15]);
    float s1 = fmaf(fmaf(fmaf(g[23], x0, g[22]), x0, g[21]), x0, g[20]);
    float s2 = fmaf(fmaf(g[26], x0, g[25]), x0, g[24]);
    float s3 = fmaf(g[28], x0, g[27]);
    float s4 = g[29];
    d1 = fmaf(fmaf(fmaf(fmaf(s4, x1, s3), x1, s2), x1, s1), x1, s0);
}

__global__ void __launch_bounds__(256, 1)
sympl_main(const float* __restrict__ zin, const float* __restrict__ Gp,
           const int* __restrict__ nsp, float* __restrict__ zout, int batch) {
    cfloat_t* G = (cfloat_t*)(uintptr_t)Gp;

    int lt = threadIdx.x;
    int idx = blockIdx.x * 256 + lt;
    bool active = idx < batch;

    float4 zv = make_float4(0.f, 0.f, 0.f, 0.f);
    if (active) zv = reinterpret_cast<const float4*>(zin)[idx];
    float dt  = 1.0f / (32.0f * (float)nsp[0]);
    float hdt = 0.5f * dt;

    float q0 = zv.x, q1 = zv.y, p0 = zv.z, p1 = zv.w;

    float gX[30], gY[30];
    loadc(G, gX);                                  // stage 0 (step 0, A)

#pragma unroll 1
    for (int s = 0; s < NSTEP; ++s) {
        cfloat_t* base = G + s * 128;

        // ---- stage A (from X); prefetch B into Y ----
        loadc(base + 32, gY);
        float dA0, dA1; pgrad(gX, p0, p1, dA0, dA1);
        q0 = fmaf(dA0, hdt, q0); q1 = fmaf(dA1, hdt, q1);

        // ---- stage B (from Y); prefetch C into X ----
        loadc(base + 64, gX);
        float dB0, dB1; pgrad(gY, q0, q1, dB0, dB1);
        p0 = fmaf(-dB0, dt, p0); p1 = fmaf(-dB1, dt, p1);
        q0 = fmaf(dA0, hdt, q0); q1 = fmaf(dA1, hdt, q1);

        float u0 = q1, u1 = p0, v0 = q0, v1 = p1;

        // ---- stage C (from X); prefetch D into Y ----
        loadc(base + 96, gY);
        float dC0, dC1; pgrad(gX, v0, v1, dC0, dC1);
        u0 = fmaf(dC1, hdt, u0); u1 = fmaf(-dC0, hdt, u1);

        // ---- stage D (from Y); prefetch next step's A into X ----
        cfloat_t* nbase = (s + 1 < NSTEP) ? base + 128 : base;
        loadc(nbase, gX);
        float dD0, dD1; pgrad(gY, u0, u1, dD0, dD1);
        v0 = fmaf(dD1, dt, v0); v1 = fmaf(-dD0, dt, v1);
        u0 = fmaf(dC1, hdt, u0); u1 = fmaf(-dC0, hdt, u1);

        q0 = v0; q1 = u0; p0 = u1; p1 = v1;        // z = [v0, u0, u1, v1]
    }

    if (active) {
        float4 o; o.x = q0; o.y = q1; o.z = p0; o.w = p1;
        reinterpret_cast<float4*>(zout)[idx] = o;
    }
}

extern "C" void kernel_launch(void* const* d_in, const int* in_sizes, int n_in,
                              void* d_out, int out_size, void* d_ws, size_t ws_size,
                              hipStream_t stream) {
    const float* z  = (const float*)d_in[0];
    const float* Aw = (const float*)d_in[1];
    const float* Bw = (const float*)d_in[2];
    const float* Cw = (const float*)d_in[3];
    const float* Dw = (const float*)d_in[4];
    const int*   ns = (const int*)d_in[5];
    float* G = (float*)d_ws;   // 128 * 32 floats = 16 KB

    prep_kernel<<<1, 128, 0, stream>>>(Aw, Bw, Cw, Dw, G);

    int batch = in_sizes[0] / 4;
    int threads = 256;
    int blocks = (batch + threads - 1) / threads;
    sympl_main<<<blocks, threads, 0, stream>>>(z, G, ns, (float*)d_out, batch);
}

// Round 7
// 26.075 us; speedup vs baseline: 1.6324x; 1.6323x over previous
//
#include <hip/hip_runtime.h>

#define NSTEP 32
// DIM = 62 monomials of degree 1..5 over (x0,x1); collapsed to 30 gradient
// coefficients per (step, stage). LDS layout (tightly packed):
//   sG[step*120 + stage*30 + k]
// k=0..14  -> dP/dx0 (triangular rows by e0, widths 5,4,3,2,1; inner Horner in x1)
// k=15..29 -> dP/dx1 (rows by e1; inner Horner in x0)
// 120 floats/step = 480 B -> 30 ds_read_b128 per step per wave.
//
// KEY STRUCTURE: 2 samples per lane. 32768 threads = 512 waves = 2 waves/CU,
// halving per-CU LDS-pipe pressure (the measured 20.6us bound was 4 waves/CU
// x 960 ds_read_b128 x ~12cyc). FMA work doubles per wave but stays below the
// LDS bound; two independent samples double ILP.

__device__ __forceinline__ void loadstep(const float* __restrict__ sg, float (&R)[120]) {
#pragma unroll
    for (int i = 0; i < 30; ++i) {
        float4 v = *reinterpret_cast<const float4*>(sg + i * 4);
        R[i * 4 + 0] = v.x; R[i * 4 + 1] = v.y;
        R[i * 4 + 2] = v.z; R[i * 4 + 3] = v.w;
    }
}

template <int B>
__device__ __forceinline__ void pgrad(const float (&g)[120], float x0, float x1,
                                      float& d0, float& d1) {
    float r0 = fmaf(fmaf(fmaf(fmaf(g[B+4], x1, g[B+3]), x1, g[B+2]), x1, g[B+1]), x1, g[B+0]);
    float r1 = fmaf(fmaf(fmaf(g[B+8], x1, g[B+7]), x1, g[B+6]), x1, g[B+5]);
    float r2 = fmaf(fmaf(g[B+11], x1, g[B+10]), x1, g[B+9]);
    float r3 = fmaf(g[B+13], x1, g[B+12]);
    float r4 = g[B+14];
    d0 = fmaf(fmaf(fmaf(fmaf(r4, x0, r3), x0, r2), x0, r1), x0, r0);

    float s0 = fmaf(fmaf(fmaf(fmaf(g[B+19], x0, g[B+18]), x0, g[B+17]), x0, g[B+16]), x0, g[B+15]);
    float s1 = fmaf(fmaf(fmaf(g[B+23], x0, g[B+22]), x0, g[B+21]), x0, g[B+20]);
    float s2 = fmaf(fmaf(g[B+26], x0, g[B+25]), x0, g[B+24]);
    float s3 = fmaf(g[B+28], x0, g[B+27]);
    float s4 = g[B+29];
    d1 = fmaf(fmaf(fmaf(fmaf(s4, x1, s3), x1, s2), x1, s1), x1, s0);
}

// One macro-step for BOTH samples; per-stage the two samples' Horner chains
// are adjacent -> compiler interleaves them (2x ILP).
__device__ __forceinline__ void dostep2(const float (&g)[120],
                                        float (&q0)[2], float (&q1)[2],
                                        float (&p0)[2], float (&p1)[2],
                                        float dt, float hdt) {
    float dA0[2], dA1[2];
#pragma unroll
    for (int j = 0; j < 2; ++j) {
        pgrad<0>(g, p0[j], p1[j], dA0[j], dA1[j]);
        q0[j] = fmaf(dA0[j], hdt, q0[j]); q1[j] = fmaf(dA1[j], hdt, q1[j]);
    }
#pragma unroll
    for (int j = 0; j < 2; ++j) {
        float dB0, dB1; pgrad<30>(g, q0[j], q1[j], dB0, dB1);
        p0[j] = fmaf(-dB0, dt, p0[j]); p1[j] = fmaf(-dB1, dt, p1[j]);
        q0[j] = fmaf(dA0[j], hdt, q0[j]); q1[j] = fmaf(dA1[j], hdt, q1[j]);
    }
    float u0[2], u1[2], v0[2], v1[2], dC0[2], dC1[2];
#pragma unroll
    for (int j = 0; j < 2; ++j) {
        u0[j] = q1[j]; u1[j] = p0[j]; v0[j] = q0[j]; v1[j] = p1[j];
        pgrad<60>(g, v0[j], v1[j], dC0[j], dC1[j]);
        u0[j] = fmaf(dC1[j], hdt, u0[j]); u1[j] = fmaf(-dC0[j], hdt, u1[j]);
    }
#pragma unroll
    for (int j = 0; j < 2; ++j) {
        float dD0, dD1; pgrad<90>(g, u0[j], u1[j], dD0, dD1);
        v0[j] = fmaf(dD1, dt, v0[j]); v1[j] = fmaf(-dD0, dt, v1[j]);
        u0[j] = fmaf(dC1[j], hdt, u0[j]); u1[j] = fmaf(-dC0[j], hdt, u1[j]);
        q0[j] = v0[j]; q1[j] = u0[j]; p0[j] = u1[j]; p1[j] = v1[j];
    }
}

__global__ void __launch_bounds__(128, 1)
sympl_fused(const float* __restrict__ zin,
            const float* __restrict__ Aw, const float* __restrict__ Bw,
            const float* __restrict__ Cw, const float* __restrict__ Dw,
            const int* __restrict__ nsp,
            float* __restrict__ zout, int batch) {
    __shared__ float sG[NSTEP * 120];

    int lt = threadIdx.x;
    int base = blockIdx.x * 256;
    int i0 = base + lt, i1 = base + 128 + lt;
    bool a0 = i0 < batch, a1 = i1 < batch;

    // issue z loads first (independent of prep)
    float4 zv0 = make_float4(0.f, 0.f, 0.f, 0.f);
    float4 zv1 = make_float4(0.f, 0.f, 0.f, 0.f);
    if (a0) zv0 = reinterpret_cast<const float4*>(zin)[i0];
    if (a1) zv1 = reinterpret_cast<const float4*>(zin)[i1];
    float dt  = 1.0f / (32.0f * (float)nsp[0]);
    float hdt = 0.5f * dt;

    // ---- per-block prep: 128 (step,stage) collapse tasks, 1 per thread ----
    {
        int stepi = lt >> 2, which = lt & 3;
        const float* w;
        switch (which) { case 0: w = Aw; break; case 1: w = Bw; break;
                         case 2: w = Cw; break; default: w = Dw; }
        w += stepi * 62;

        float c[6][6];
#pragma unroll
        for (int a = 0; a < 6; ++a)
#pragma unroll
            for (int b = 0; b < 6; ++b) c[a][b] = 0.f;
        // degree-d flat index f: bits of f are monomial indices; popcount = power of x1
#pragma unroll
        for (int d = 1; d <= 5; ++d)
#pragma unroll
            for (int f = 0; f < (1 << d); ++f) {
                int b = __popc(f);
                c[d - b][b] += w[(1 << d) - 2 + f];
            }

        float* dst = sG + stepi * 120 + which * 30;
        int k = 0;
#pragma unroll
        for (int e0 = 0; e0 <= 4; ++e0)
#pragma unroll
            for (int e1 = 0; e1 + e0 <= 4; ++e1)
                dst[k++] = (float)(e0 + 1) * c[e0 + 1][e1];
#pragma unroll
        for (int e1 = 0; e1 <= 4; ++e1)
#pragma unroll
            for (int e0 = 0; e0 + e1 <= 4; ++e0)
                dst[k++] = (float)(e1 + 1) * c[e0][e1 + 1];
    }
    __syncthreads();

    float q0[2] = {zv0.x, zv1.x}, q1[2] = {zv0.y, zv1.y};
    float p0[2] = {zv0.z, zv1.z}, p1[2] = {zv0.w, zv1.w};

    // ---- main loop: full-step register double buffer, unroll x2 ----
    float bufX[120], bufY[120];
    loadstep(sG, bufX);

#pragma unroll 1
    for (int it = 0; it < NSTEP / 2; ++it) {
        int s = 2 * it;
        loadstep(sG + (s + 1) * 120, bufY);
        dostep2(bufX, q0, q1, p0, p1, dt, hdt);
        int sn = (s + 2 < NSTEP) ? s + 2 : NSTEP - 1;
        loadstep(sG + sn * 120, bufX);
        dostep2(bufY, q0, q1, p0, p1, dt, hdt);
    }

    if (a0) {
        float4 o; o.x = q0[0]; o.y = q1[0]; o.z = p0[0]; o.w = p1[0];
        reinterpret_cast<float4*>(zout)[i0] = o;
    }
    if (a1) {
        float4 o; o.x = q0[1]; o.y = q1[1]; o.z = p0[1]; o.w = p1[1];
        reinterpret_cast<float4*>(zout)[i1] = o;
    }
}

extern "C" void kernel_launch(void* const* d_in, const int* in_sizes, int n_in,
                              void* d_out, int out_size, void* d_ws, size_t ws_size,
                              hipStream_t stream) {
    const float* z  = (const float*)d_in[0];
    const float* Aw = (const float*)d_in[1];
    const float* Bw = (const float*)d_in[2];
    const float* Cw = (const float*)d_in[3];
    const float* Dw = (const float*)d_in[4];
    const int*   ns = (const int*)d_in[5];

    int batch = in_sizes[0] / 4;
    int blocks = (batch + 255) / 256;   // 128 threads, 2 samples/thread
    sympl_fused<<<blocks, 128, 0, stream>>>(z, Aw, Bw, Cw, Dw, ns,
                                            (float*)d_out, batch);
}